// Round 8
// baseline (3964.558 us; speedup 1.0000x reference)
//
#include <hip/hip_runtime.h>
#include <math.h>

typedef __attribute__((ext_vector_type(4))) float f32x4;
typedef __attribute__((ext_vector_type(4))) int   i32x4;
typedef __attribute__((ext_vector_type(8))) short bfrag8;   // 8 bf16 = 4 VGPRs

// ---- ws layout (bytes) ----
// wre_hi: 5 mats * 1024 * 256 * 2B = 2621440 @ 0
// wre_lo: same                              @ 2621440
// hb    : 4 planes * 3 layers * 256*256 * 2B = 1572864 @ 5242880
// tags  : 12 groups * 64 dwords (main 0..31, shadow 32..63) = 3072 B @ 6815744
#define WRE_LO_OFF 2621440
#define HB_OFF     5242880
#define TAG_OFF    6815744
#define HSTRIDE    65536          // shorts per (plane,layer) slot

// dynamic LDS: [2 mats][2 planes][64 rows][264 bf16]  = 4*64*264*2 = 135168 B
#define WROW 264
#define SMEM_BYTES (4 * 64 * WROW * 2)

__device__ __forceinline__ unsigned short f2bf(float f){
  union { float f; unsigned u; } x; x.f = f;
  unsigned r = x.u + 0x7FFFu + ((x.u >> 16) & 1u);   // RNE
  return (unsigned short)(r >> 16);
}
__device__ __forceinline__ float bf2f(unsigned short s){
  union { unsigned u; float f; } x; x.u = ((unsigned)s) << 16; return x.f;
}
__device__ __forceinline__ float sigf(float x){
  return 1.0f / (1.0f + __expf(-x));
}
__device__ __forceinline__ float tanh_fast(float x){
  x = fminf(fmaxf(x, -15.0f), 15.0f);
  float e = __expf(2.0f * x);
  return (e - 1.0f) / (e + 1.0f);
}

// ---- LLC-direct (coherence-point) access: sc0 sc1 bypasses L1 and L2.
__device__ __forceinline__ i32x4 llc_load_b128(const void* p){
  i32x4 r;
  asm volatile("global_load_dwordx4 %0, %1, off sc0 sc1"
               : "=v"(r) : "v"(p) : "memory");
  return r;
}
__device__ __forceinline__ void llc_store_b16(void* p, unsigned short v){
  unsigned int vv = v;
  asm volatile("global_store_short %0, %1, off sc0 sc1"
               : : "v"(p), "v"(vv) : "memory");
}
__device__ __forceinline__ void wait_vm0(){
  asm volatile("s_waitcnt vmcnt(0)" ::: "memory");
}
__device__ __forceinline__ f32x4 mf(bfrag8 a, bfrag8 b, f32x4 c){
  return __builtin_amdgcn_mfma_f32_16x16x32_bf16(a, b, c, 0, 0, 0);
}

// Reorder the 5 big weight mats into per-(nt)-contiguous rows, split bf16 hi/lo.
__global__ void init_reorder(const float* __restrict__ hh0, const float* __restrict__ ih1,
                             const float* __restrict__ hh1, const float* __restrict__ ih2,
                             const float* __restrict__ hh2,
                             unsigned short* __restrict__ wre_hi,
                             unsigned short* __restrict__ wre_lo){
  int e = blockIdx.x * 256 + threadIdx.x;        // 5*2^18 total
  int mat = e >> 18;
  int d   = (e >> 8) & 1023;
  int k   = e & 255;
  int nt = d >> 6, g = (d >> 4) & 3, n = d & 15;
  int src_row = g*256 + nt*16 + n;
  const float* W = (mat==0) ? hh0 : (mat==1) ? ih1 : (mat==2) ? hh1 : (mat==3) ? ih2 : hh2;
  float v = W[src_row*256 + k];
  unsigned short hi = f2bf(v);
  float lo = v - bf2f(hi);
  wre_hi[e] = hi;
  wre_lo[e] = f2bf(lo);
}

__global__ void init_zero(uint4* __restrict__ p, int n16){
  int i = blockIdx.x * 256 + threadIdx.x;
  if (i < n16) p[i] = make_uint4(0u,0u,0u,0u);
}

// Skew-2 layer-pipelined LSTM. 192 blocks x 128 threads = layer(3) x nt(16) x bt(4).
// Layer L processes t = s - 2L at iteration s (516 iters). 4 h planes (t mod 4).
// Group (L,bt) owns a 64-dword tag region: main slots [w*16+nt] (posted after
// main h-stores drained), shadow slots [32+w*16+nt] (posted after shadow A-loads
// drained). Waits (per wave, relaxed agent loads, s_sleep(1)):
//   top : own-main >= s                        (recurrent h_L[t-1] ready)
//   tail: up-main >= s, down-shadow >= s-1     (shadow operand ready; WAR guard
//                                               for next iter's plane overwrite)
// Shadow phase (L>=1): prefetch h_{L-1}[t+1] + input-matmul into xacc for the
// NEXT iteration -> cross-layer LLC latency + half the MFMA/LDS leave the
// critical path. No __syncthreads in the loop; no RMWs (slot stores).
template<int L>
__device__ __forceinline__ void layer_loop(
    const float* __restrict__ tracks, const float* __restrict__ wih0,
    const float* __restrict__ bihL, const float* __restrict__ bhhL,
    const unsigned short* smem,
    unsigned short* hb, unsigned int* tags,
    int nt, int bt)
{
  const int tid  = threadIdx.x;
  const int w    = tid >> 6, lane = tid & 63;
  const int m    = lane & 15, q = lane >> 4;
  const int b0   = bt * 64, n0 = nt * 16;
  const int bw   = b0 + 32*w;                    // this wave's 32 batch rows

  const int gid = L*4 + bt;
  unsigned int* own = tags + gid*64;
  unsigned int* upb = (L >= 1) ? (tags + (gid-4)*64) : tags;
  unsigned int* dnb = (L <= 1) ? (tags + (gid+4)*64) : tags;
  const int mslot = w*16 + nt;
  const int sslot = 32 + w*16 + nt;

  float bsum[4], wxa[4], wxb[4];
  #pragma unroll
  for (int g = 0; g < 4; ++g){
    int row = g*256 + n0 + m;
    bsum[g] = bihL[row] + bhhL[row];
    if constexpr (L == 0){ wxa[g] = wih0[row*2 + 0]; wxb[g] = wih0[row*2 + 1]; }
    else { wxa[g] = 0.f; wxb[g] = 0.f; }
  }
  float cst[2][4];
  f32x4 xacc[2][4];
  #pragma unroll
  for (int j = 0; j < 2; ++j){
    #pragma unroll
    for (int r = 0; r < 4; ++r) cst[j][r] = 0.f;
    #pragma unroll
    for (int g = 0; g < 4; ++g) xacc[j][g] = (f32x4){0.f,0.f,0.f,0.f};
  }

  const int woff = m*WROW + q*8;
  constexpr int RS = (L == 0) ? 0 : 2;     // recurrent-mat LDS slot base

  for (int s = 0; s < 516; ++s){
    const int ph = s - 2*L;
    const bool mact = (ph >= 0) && (ph < 512);

    // ---- x prefetch (L0; read-only, before any wait) ----
    float xv0[2][4], xv1[2][4];
    if constexpr (L == 0){
      if (mact){
        #pragma unroll
        for (int j = 0; j < 2; ++j)
          #pragma unroll
          for (int r = 0; r < 4; ++r){
            const float* px = tracks + (bw + 16*j + q*4 + r)*1024 + ph*2;
            xv0[j][r] = px[0]; xv1[j][r] = px[1];
          }
      }
    }

    // ---- TOP poll: own group's main arrivals >= s (recurrent ready) ----
    if (mact && s > 0){
      const int tgt = s;
      for (;;){
        int v = tgt;
        if (lane < 32)
          v = (int)__hip_atomic_load(own + lane, __ATOMIC_RELAXED, __HIP_MEMORY_SCOPE_AGENT);
        if (__all((int)(v >= tgt))) break;
        __builtin_amdgcn_s_sleep(1);
      }
    }

    if (mact){
      const int pt = ph & 3, pp = (ph + 3) & 3;

      // recurrent A: h_L[t-1], 2 batch tiles x 8 k-slices, LLC-direct
      i32x4 arr[2][8];
      const unsigned short* pr = hb + (pp*3 + L)*HSTRIDE;
      #pragma unroll
      for (int j = 0; j < 2; ++j)
        #pragma unroll
        for (int ks = 0; ks < 8; ++ks)
          arr[j][ks] = llc_load_b128(pr + (bw + 16*j + m)*256 + ks*32 + q*8);
      wait_vm0();

      f32x4 acc[2][4];
      #pragma unroll
      for (int j = 0; j < 2; ++j)
        #pragma unroll
        for (int g = 0; g < 4; ++g) acc[j][g] = (f32x4){0.f,0.f,0.f,0.f};

      // rec MFMA: read each B-frag once, use for both batch tiles
      const unsigned short* bh = smem + (RS + 0)*64*WROW + woff;
      const unsigned short* bl = smem + (RS + 1)*64*WROW + woff;
      #pragma unroll
      for (int ks = 0; ks < 8; ++ks){
        bfrag8 a0 = __builtin_bit_cast(bfrag8, arr[0][ks]);
        bfrag8 a1 = __builtin_bit_cast(bfrag8, arr[1][ks]);
        #pragma unroll
        for (int g = 0; g < 4; ++g){
          bfrag8 fh = *(const bfrag8*)(bh + g*16*WROW + ks*32);
          bfrag8 fl = *(const bfrag8*)(bl + g*16*WROW + ks*32);
          acc[0][g] = mf(a0, fh, acc[0][g]);
          acc[1][g] = mf(a1, fh, acc[1][g]);
          acc[0][g] = mf(a0, fl, acc[0][g]);
          acc[1][g] = mf(a1, fl, acc[1][g]);
        }
      }

      // cell update; gates = rec + (shadow xacc | x-term) + bias
      unsigned short* hout = hb + (pt*3 + L)*HSTRIDE;
      #pragma unroll
      for (int j = 0; j < 2; ++j){
        #pragma unroll
        for (int r = 0; r < 4; ++r){
          float xi, xf, xg, xo;
          if constexpr (L == 0){
            xi = xv0[j][r]*wxa[0] + xv1[j][r]*wxb[0];
            xf = xv0[j][r]*wxa[1] + xv1[j][r]*wxb[1];
            xg = xv0[j][r]*wxa[2] + xv1[j][r]*wxb[2];
            xo = xv0[j][r]*wxa[3] + xv1[j][r]*wxb[3];
          } else {
            xi = xacc[j][0][r]; xf = xacc[j][1][r];
            xg = xacc[j][2][r]; xo = xacc[j][3][r];
          }
          float gi = acc[j][0][r] + bsum[0] + xi;
          float gf = acc[j][1][r] + bsum[1] + xf;
          float gg = acc[j][2][r] + bsum[2] + xg;
          float go = acc[j][3][r] + bsum[3] + xo;
          float iv = sigf(gi);
          float fv = sigf(gf);
          float gv = tanh_fast(gg);
          float ov = sigf(go);
          cst[j][r] = fv * cst[j][r] + iv * gv;
          float hv = ov * tanh_fast(cst[j][r]);
          llc_store_b16(&hout[(bw + 16*j + q*4 + r)*256 + n0 + m], f2bf(hv));
        }
      }
    }

    // ---- main arrival: this wave's stores drained -> post main slot ----
    wait_vm0();
    if (lane == 0)
      __hip_atomic_store(own + mslot, (unsigned)(s + 1),
                         __ATOMIC_RELAXED, __HIP_MEMORY_SCOPE_AGENT);

    // ---- TAIL poll: up-main >= s (shadow operand), down-shadow >= s-1 (WAR) ----
    {
      const int tgtU = s, tgtD = s - 1;
      const bool needU = (L >= 1) && (tgtU > 0);
      const bool needD = (L <= 1) && (tgtD > 0);
      if (needU || needD){
        for (;;){
          bool ok = true;
          if (needU && lane < 32)
            ok = ((int)__hip_atomic_load(upb + lane, __ATOMIC_RELAXED,
                                         __HIP_MEMORY_SCOPE_AGENT) >= tgtU);
          if (needD && lane >= 32)
            ok = ((int)__hip_atomic_load(dnb + lane, __ATOMIC_RELAXED,
                                         __HIP_MEMORY_SCOPE_AGENT) >= tgtD);
          if (__all((int)ok)) break;
          __builtin_amdgcn_s_sleep(1);
        }
      }
    }

    // ---- shadow phase (L>=1): prefetch h_{L-1}[t+1], input-matmul into xacc ----
    bool posted_shadow = false;
    if constexpr (L >= 1){
      if (ph >= -1 && ph < 511){
        const int pin = (ph + 1) & 3;
        i32x4 ash[2][8];
        const unsigned short* pi = hb + (pin*3 + (L-1))*HSTRIDE;
        #pragma unroll
        for (int j = 0; j < 2; ++j)
          #pragma unroll
          for (int ks = 0; ks < 8; ++ks)
            ash[j][ks] = llc_load_b128(pi + (bw + 16*j + m)*256 + ks*32 + q*8);
        wait_vm0();   // shadow loads secured -> plane may be recycled upstream
        if (lane == 0)
          __hip_atomic_store(own + sslot, (unsigned)(s + 1),
                             __ATOMIC_RELAXED, __HIP_MEMORY_SCOPE_AGENT);
        posted_shadow = true;

        #pragma unroll
        for (int j = 0; j < 2; ++j)
          #pragma unroll
          for (int g = 0; g < 4; ++g) xacc[j][g] = (f32x4){0.f,0.f,0.f,0.f};
        const unsigned short* ih = smem + 0*64*WROW + woff;
        const unsigned short* il = smem + 1*64*WROW + woff;
        #pragma unroll
        for (int ks = 0; ks < 8; ++ks){
          bfrag8 a0 = __builtin_bit_cast(bfrag8, ash[0][ks]);
          bfrag8 a1 = __builtin_bit_cast(bfrag8, ash[1][ks]);
          #pragma unroll
          for (int g = 0; g < 4; ++g){
            bfrag8 fh = *(const bfrag8*)(ih + g*16*WROW + ks*32);
            bfrag8 fl = *(const bfrag8*)(il + g*16*WROW + ks*32);
            xacc[0][g] = mf(a0, fh, xacc[0][g]);
            xacc[1][g] = mf(a1, fh, xacc[1][g]);
            xacc[0][g] = mf(a0, fl, xacc[0][g]);
            xacc[1][g] = mf(a1, fl, xacc[1][g]);
          }
        }
      }
    }
    if (!posted_shadow && lane == 0)
      __hip_atomic_store(own + sslot, (unsigned)(s + 1),
                         __ATOMIC_RELAXED, __HIP_MEMORY_SCOPE_AGENT);
  }
}

__global__ void __launch_bounds__(128, 1) lstm_coop(
    const float* __restrict__ tracks,
    const float* __restrict__ wih0,
    const float* __restrict__ bih0, const float* __restrict__ bhh0,
    const float* __restrict__ bih1, const float* __restrict__ bhh1,
    const float* __restrict__ bih2, const float* __restrict__ bhh2,
    const unsigned short* __restrict__ wre_hi, const unsigned short* __restrict__ wre_lo,
    unsigned short* __restrict__ hb, unsigned int* __restrict__ tags)
{
  extern __shared__ __align__(16) unsigned short smem[];   // [mat][plane][64][WROW]

  const int tid = threadIdx.x;
  const int l   = blockIdx.x >> 6;
  const int r6  = blockIdx.x & 63;
  const int nt  = r6 & 15, bt = r6 >> 4;

  // ---- stage this layer's weight slices into LDS (once) ----
  const int nmats = (l == 0) ? 1 : 2;
  const int gmat0 = (l == 0) ? 0 : (l == 1 ? 1 : 3);
  for (int mi = 0; mi < nmats; ++mi){
    const unsigned short* sh = wre_hi + (gmat0 + mi)*262144 + nt*16384;
    const unsigned short* sl = wre_lo + (gmat0 + mi)*262144 + nt*16384;
    unsigned short* dh = smem + (mi*2 + 0)*64*WROW;
    unsigned short* dl = smem + (mi*2 + 1)*64*WROW;
    for (int c = tid; c < 2048; c += 128){
      int r = c >> 5, off = (c & 31) * 8;
      *(uint4*)(dh + r*WROW + off) = *(const uint4*)(sh + r*256 + off);
      *(uint4*)(dl + r*WROW + off) = *(const uint4*)(sl + r*256 + off);
    }
  }
  __syncthreads();

  if (l == 0)      layer_loop<0>(tracks, wih0, bih0, bhh0, smem, hb, tags, nt, bt);
  else if (l == 1) layer_loop<1>(tracks, wih0, bih1, bhh1, smem, hb, tags, nt, bt);
  else             layer_loop<2>(tracks, wih0, bih2, bhh2, smem, hb, tags, nt, bt);
}

// out[b] = elu(h2_final[b]) @ W_pred^T + b_pred ; h2[511] plane = 511&3 = 3 -> slot 3*3+2 = 11
__global__ void head_kernel(const unsigned short* __restrict__ hb,
                            const float* __restrict__ wpred,
                            const float* __restrict__ bpred,
                            float* __restrict__ out){
  const int b = blockIdx.x;
  const int k = threadIdx.x;
  const int idx = 11*HSTRIDE + b*256 + k;
  float h = bf2f(hb[idx]);
  float e = (h > 0.f) ? h : expm1f(h);
  float v0 = e * wpred[k];
  float v1 = e * wpred[256 + k];
  #pragma unroll
  for (int off = 32; off > 0; off >>= 1){
    v0 += __shfl_down(v0, off, 64);
    v1 += __shfl_down(v1, off, 64);
  }
  __shared__ float r0[4], r1[4];
  int wv = threadIdx.x >> 6, ln = threadIdx.x & 63;
  if (ln == 0){ r0[wv] = v0; r1[wv] = v1; }
  __syncthreads();
  if (threadIdx.x == 0){
    out[b*2 + 0] = r0[0] + r0[1] + r0[2] + r0[3] + bpred[0];
    out[b*2 + 1] = r1[0] + r1[1] + r1[2] + r1[3] + bpred[1];
  }
}

extern "C" void kernel_launch(void* const* d_in, const int* in_sizes, int n_in,
                              void* d_out, int out_size, void* d_ws, size_t ws_size,
                              hipStream_t stream) {
  const float* tracks = (const float*)d_in[0];
  const float* wih0   = (const float*)d_in[1];
  const float* whh0   = (const float*)d_in[2];
  const float* bih0   = (const float*)d_in[3];
  const float* bhh0   = (const float*)d_in[4];
  const float* wih1   = (const float*)d_in[5];
  const float* whh1   = (const float*)d_in[6];
  const float* bih1   = (const float*)d_in[7];
  const float* bhh1   = (const float*)d_in[8];
  const float* wih2   = (const float*)d_in[9];
  const float* whh2   = (const float*)d_in[10];
  const float* bih2   = (const float*)d_in[11];
  const float* bhh2   = (const float*)d_in[12];
  const float* wpred  = (const float*)d_in[13];
  const float* bpred  = (const float*)d_in[14];
  float* out = (float*)d_out;

  char* ws = (char*)d_ws;
  unsigned short* wre_hi = (unsigned short*)(ws);
  unsigned short* wre_lo = (unsigned short*)(ws + WRE_LO_OFF);
  unsigned short* hb     = (unsigned short*)(ws + HB_OFF);
  unsigned int*   tags   = (unsigned int*)(ws + TAG_OFF);

  (void)hipFuncSetAttribute((const void*)lstm_coop,
                            hipFuncAttributeMaxDynamicSharedMemorySize, SMEM_BYTES);

  init_reorder<<<5120, 256, 0, stream>>>(whh0, wih1, whh1, wih2, whh2, wre_hi, wre_lo);
  // zero hb (1572864 B) + tags (3072 B) = 1575936 B = 98496 uint4
  init_zero<<<385, 256, 0, stream>>>((uint4*)(ws + HB_OFF), 98496);

  void* args[12];
  args[0]  = (void*)&tracks;
  args[1]  = (void*)&wih0;
  args[2]  = (void*)&bih0;
  args[3]  = (void*)&bhh0;
  args[4]  = (void*)&bih1;
  args[5]  = (void*)&bhh1;
  args[6]  = (void*)&bih2;
  args[7]  = (void*)&bhh2;
  args[8]  = (void*)&wre_hi;
  args[9]  = (void*)&wre_lo;
  args[10] = (void*)&hb;
  args[11] = (void*)&tags;
  // cooperative launch kept purely for the all-blocks-co-resident guarantee
  hipLaunchCooperativeKernel((const void*)lstm_coop, dim3(192), dim3(128), args,
                             SMEM_BYTES, stream);

  head_kernel<<<256, 256, 0, stream>>>(hb, wpred, bpred, out);
}

// Round 12
// 3391.673 us; speedup vs baseline: 1.1689x; 1.1689x over previous
//
#include <hip/hip_runtime.h>
#include <math.h>

typedef __attribute__((ext_vector_type(4))) float f32x4;
typedef __attribute__((ext_vector_type(4))) int   i32x4;
typedef __attribute__((ext_vector_type(8))) short bfrag8;   // 8 bf16 = 4 VGPRs

// ---- ws layout (bytes) ----
// wre_hi: 5 mats * 1024 * 256 * 2B = 2621440 @ 0
// wre_lo: same                              @ 2621440
// hb    : 2 par * 3 layers * 256*256 * 2B = 786432 @ 5242880
// flags : 4 columns * 16 subcounters * 64 uints = 16384 B @ 6029312
#define WRE_LO_OFF 2621440
#define HB_OFF     5242880
#define FLAGS_OFF  6029312

// dynamic LDS: [2 mats][2 planes][64 rows][264 bf16]  = 4*64*264*2 = 135168 B
#define WROW 264
#define SMEM_BYTES (4 * 64 * WROW * 2)

__device__ __forceinline__ unsigned short f2bf(float f){
  union { float f; unsigned u; } x; x.f = f;
  unsigned r = x.u + 0x7FFFu + ((x.u >> 16) & 1u);   // RNE
  return (unsigned short)(r >> 16);
}
__device__ __forceinline__ float bf2f(unsigned short s){
  union { unsigned u; float f; } x; x.u = ((unsigned)s) << 16; return x.f;
}
__device__ __forceinline__ float sigf(float x){
  return 1.0f / (1.0f + __expf(-x));
}
__device__ __forceinline__ float tanh_fast(float x){
  x = fminf(fmaxf(x, -15.0f), 15.0f);
  float e = __expf(2.0f * x);
  return (e - 1.0f) / (e + 1.0f);
}

// ---- LLC-direct (coherence-point) access: sc0 sc1 bypasses L1 and L2.
// Cross-XCD visibility without buffer_wbl2 / buffer_inv fences.
__device__ __forceinline__ i32x4 llc_load_b128(const void* p){
  i32x4 r;
  asm volatile("global_load_dwordx4 %0, %1, off sc0 sc1"
               : "=v"(r) : "v"(p) : "memory");
  return r;
}
__device__ __forceinline__ void llc_store_b16(void* p, unsigned short v){
  unsigned int vv = v;
  asm volatile("global_store_short %0, %1, off sc0 sc1"
               : : "v"(p), "v"(vv) : "memory");
}
__device__ __forceinline__ void wait_vm0(){
  asm volatile("s_waitcnt vmcnt(0)" ::: "memory");
}

// Reorder the 5 big weight mats into per-(nt)-contiguous rows, split bf16 hi/lo.
__global__ void init_reorder(const float* __restrict__ hh0, const float* __restrict__ ih1,
                             const float* __restrict__ hh1, const float* __restrict__ ih2,
                             const float* __restrict__ hh2,
                             unsigned short* __restrict__ wre_hi,
                             unsigned short* __restrict__ wre_lo){
  int e = blockIdx.x * 256 + threadIdx.x;        // 5*2^18 total
  int mat = e >> 18;
  int d   = (e >> 8) & 1023;
  int k   = e & 255;
  int nt = d >> 6, g = (d >> 4) & 3, n = d & 15;
  int src_row = g*256 + nt*16 + n;
  const float* W = (mat==0) ? hh0 : (mat==1) ? ih1 : (mat==2) ? hh1 : (mat==3) ? ih2 : hh2;
  float v = W[src_row*256 + k];
  unsigned short hi = f2bf(v);
  float lo = v - bf2f(hi);
  wre_hi[e] = hi;
  wre_lo[e] = f2bf(lo);
}

__global__ void init_zero(uint4* __restrict__ p, int n16){
  int i = blockIdx.x * 256 + threadIdx.x;
  if (i < n16) p[i] = make_uint4(0u,0u,0u,0u);
}

// Layer-pipelined LSTM. 192 blocks = layer(3) x nt(16) x bt(4).
// Block (l, nt, bt): 64 batch rows [bt*64, +64), 64 gate rows (4 gates x 16 n at nt*16).
// Weights persist in LDS (hi/lo). h lives at the LLC (sc0sc1 direct access).
// Column barrier, sharded 16 ways: sub-counter (bt,nt) gets +1 from the 3 layer
// blocks of that (bt,nt) after each step (RELAXED agent RMW — atomics execute at
// the coherence point). Wait: lanes 0..15 poll the 16 sub-counters until all
// >= 3*s. Ordering chain: h stores (LLC) -> vmcnt(0) -> RMW ; poll-observe ->
// control-dependent LLC loads. No wbl2/inv anywhere. Monotone => skew<=1 =>
// parity double-buffer RAW/WAR safe (same invariant as r4/r5).
__global__ void lstm_coop(
    const float* __restrict__ tracks,
    const float* __restrict__ wih0,
    const float* __restrict__ bih0, const float* __restrict__ bhh0,
    const float* __restrict__ bih1, const float* __restrict__ bhh1,
    const float* __restrict__ bih2, const float* __restrict__ bhh2,
    const unsigned short* __restrict__ wre_hi, const unsigned short* __restrict__ wre_lo,
    unsigned short* __restrict__ hb, unsigned int* __restrict__ flags)
{
  extern __shared__ __align__(16) unsigned short smem[];   // [mat][plane][64][WROW]

  const int tid  = threadIdx.x;
  const int l    = blockIdx.x >> 6;
  const int r6   = blockIdx.x & 63;
  const int nt   = r6 & 15, bt = r6 >> 4;
  const int b0   = bt * 64, n0 = nt * 16;
  const int w    = tid >> 6, lane = tid & 63;
  const int m    = lane & 15, q = lane >> 4;

  unsigned int* colflags = flags + bt * 1024;       // 16 sub-counters, 256B apart
  unsigned int* mycnt    = colflags + nt * 64;

  // ---- stage this layer's weight slices into LDS (once) ----
  const int nmats = (l == 0) ? 1 : 2;
  const int gmat0 = (l == 0) ? 0 : (l == 1 ? 1 : 3);
  for (int mi = 0; mi < nmats; ++mi){
    const unsigned short* sh = wre_hi + (gmat0 + mi)*262144 + nt*16384;
    const unsigned short* sl = wre_lo + (gmat0 + mi)*262144 + nt*16384;
    unsigned short* dh = smem + (mi*2 + 0)*64*WROW;
    unsigned short* dl = smem + (mi*2 + 1)*64*WROW;
    for (int c = tid; c < 2048; c += 256){
      int r = c >> 5, off = (c & 31) * 8;
      *(uint4*)(dh + r*WROW + off) = *(const uint4*)(sh + r*256 + off);
      *(uint4*)(dl + r*WROW + off) = *(const uint4*)(sl + r*256 + off);
    }
  }
  __syncthreads();

  // ---- per-lane persistent state ----
  const float* bihL = (l==0) ? bih0 : (l==1) ? bih1 : bih2;
  const float* bhhL = (l==0) ? bhh0 : (l==1) ? bhh1 : bhh2;
  float bsum[4], wx[4][2];
  #pragma unroll
  for (int g = 0; g < 4; ++g){
    int row = g*256 + n0 + m;
    bsum[g] = bihL[row] + bhhL[row];
    wx[g][0] = wih0[row*2 + 0];
    wx[g][1] = wih0[row*2 + 1];
  }
  float cst[4] = {0.f, 0.f, 0.f, 0.f};
  const int arow = b0 + 16*w + m;                  // A-fragment batch row for this lane
  const int woff = m*WROW + q*8;                   // per-lane B-frag LDS offset (shorts)

  for (int s = 0; s < 514; ++s){
    const int t = s - l;
    const bool active = (t >= 0) && (t < 512);

    // ---- x prefetch (read-only, no hazard) before the barrier ----
    float xv0[4], xv1[4];
    if (l == 0 && active){
      #pragma unroll
      for (int r = 0; r < 4; ++r){
        const float* px = tracks + (b0 + 16*w + q*4 + r)*1024 + t*2;
        xv0[r] = px[0]; xv1[r] = px[1];
      }
    }

    // ---- column barrier wait: all 16 sub-counters >= 3*s (no acquire fence;
    // h is read LLC-direct, so nothing stale can be cached) ----
    if (s > 0){
      if (tid < 64){
        const unsigned int tgt = 3u * (unsigned)s;
        for (;;){
          unsigned int v = tgt;
          if (tid < 16)
            v = __hip_atomic_load(colflags + tid*64, __ATOMIC_RELAXED,
                                  __HIP_MEMORY_SCOPE_AGENT);
          if (__all((int)(v >= tgt))) break;
          __builtin_amdgcn_s_sleep(1);
        }
      }
      __syncthreads();
    }

    if (active){
      const int pt = t & 1, pp = pt ^ 1;

      // ---- A fragments: LLC-direct loads (issued after barrier; control dep) ----
      i32x4 ar_raw[8], ai_raw[8];
      {
        const unsigned short* prec = hb + ((pp*3 + l)*256 + arow)*256 + q*8;
        #pragma unroll
        for (int ks = 0; ks < 8; ++ks)
          ar_raw[ks] = llc_load_b128(prec + ks*32);
        if (l >= 1){
          const unsigned short* pin = hb + ((pt*3 + (l-1))*256 + arow)*256 + q*8;
          #pragma unroll
          for (int ks = 0; ks < 8; ++ks)
            ai_raw[ks] = llc_load_b128(pin + ks*32);
        }
      }
      wait_vm0();

      // ---- MFMA: acc[g] over K=256, W split hi/lo ----
      f32x4 acc[4];
      #pragma unroll
      for (int g = 0; g < 4; ++g) acc[g] = (f32x4){0.f,0.f,0.f,0.f};

      { // recurrent mat: slot (l==0 ? 0 : 1)
        const unsigned short* bh = smem + ((l==0?0:2) + 0)*64*WROW + woff;
        const unsigned short* bl = smem + ((l==0?0:2) + 1)*64*WROW + woff;
        #pragma unroll
        for (int ks = 0; ks < 8; ++ks){
          bfrag8 a = __builtin_bit_cast(bfrag8, ar_raw[ks]);
          #pragma unroll
          for (int g = 0; g < 4; ++g){
            bfrag8 fh = *(const bfrag8*)(bh + g*16*WROW + ks*32);
            bfrag8 fl = *(const bfrag8*)(bl + g*16*WROW + ks*32);
            acc[g] = __builtin_amdgcn_mfma_f32_16x16x32_bf16(a, fh, acc[g], 0, 0, 0);
            acc[g] = __builtin_amdgcn_mfma_f32_16x16x32_bf16(a, fl, acc[g], 0, 0, 0);
          }
        }
      }
      if (l >= 1){ // input mat: slot 0
        const unsigned short* bh = smem + 0*64*WROW + woff;
        const unsigned short* bl = smem + 1*64*WROW + woff;
        #pragma unroll
        for (int ks = 0; ks < 8; ++ks){
          bfrag8 a = __builtin_bit_cast(bfrag8, ai_raw[ks]);
          #pragma unroll
          for (int g = 0; g < 4; ++g){
            bfrag8 fh = *(const bfrag8*)(bh + g*16*WROW + ks*32);
            bfrag8 fl = *(const bfrag8*)(bl + g*16*WROW + ks*32);
            acc[g] = __builtin_amdgcn_mfma_f32_16x16x32_bf16(a, fh, acc[g], 0, 0, 0);
            acc[g] = __builtin_amdgcn_mfma_f32_16x16x32_bf16(a, fl, acc[g], 0, 0, 0);
          }
        }
      }

      // ---- cell update (gates in registers; c exact fp32); h stores LLC-direct ----
      unsigned short* hout = hb + ((pt*3 + l)*256 + 0)*256;
      #pragma unroll
      for (int r = 0; r < 4; ++r){
        float xi = 0.f, xf = 0.f, xg = 0.f, xo = 0.f;
        if (l == 0){
          xi = xv0[r]*wx[0][0] + xv1[r]*wx[0][1];
          xf = xv0[r]*wx[1][0] + xv1[r]*wx[1][1];
          xg = xv0[r]*wx[2][0] + xv1[r]*wx[2][1];
          xo = xv0[r]*wx[3][0] + xv1[r]*wx[3][1];
        }
        float gi = acc[0][r] + bsum[0] + xi;
        float gf = acc[1][r] + bsum[1] + xf;
        float gg = acc[2][r] + bsum[2] + xg;
        float go = acc[3][r] + bsum[3] + xo;
        float iv = sigf(gi);
        float fv = sigf(gf);
        float gvv = tanh_fast(gg);
        float ov = sigf(go);
        cst[r] = fv * cst[r] + iv * gvv;
        float hv = ov * tanh_fast(cst[r]);
        llc_store_b16(&hout[(b0 + 16*w + q*4 + r)*256 + n0 + m], f2bf(hv));
      }
    }

    // ---- arrive: each thread drains its own LLC stores, block barrier orders
    // all waves, then one RELAXED release-free RMW on this (bt,nt)'s line ----
    wait_vm0();
    __syncthreads();
    if (tid == 0)
      __hip_atomic_fetch_add(mycnt, 1u, __ATOMIC_RELAXED, __HIP_MEMORY_SCOPE_AGENT);
  }
}

// out[b] = elu(h2_final[b]) @ W_pred^T + b_pred ; h2 final parity = 511&1 = 1 -> plane 5
__global__ void head_kernel(const unsigned short* __restrict__ hb,
                            const float* __restrict__ wpred,
                            const float* __restrict__ bpred,
                            float* __restrict__ out){
  const int b = blockIdx.x;
  const int k = threadIdx.x;
  const int idx = (5*256 + b)*256 + k;
  float h = bf2f(hb[idx]);
  float e = (h > 0.f) ? h : expm1f(h);
  float v0 = e * wpred[k];
  float v1 = e * wpred[256 + k];
  #pragma unroll
  for (int off = 32; off > 0; off >>= 1){
    v0 += __shfl_down(v0, off, 64);
    v1 += __shfl_down(v1, off, 64);
  }
  __shared__ float r0[4], r1[4];
  int wv = threadIdx.x >> 6, ln = threadIdx.x & 63;
  if (ln == 0){ r0[wv] = v0; r1[wv] = v1; }
  __syncthreads();
  if (threadIdx.x == 0){
    out[b*2 + 0] = r0[0] + r0[1] + r0[2] + r0[3] + bpred[0];
    out[b*2 + 1] = r1[0] + r1[1] + r1[2] + r1[3] + bpred[1];
  }
}

extern "C" void kernel_launch(void* const* d_in, const int* in_sizes, int n_in,
                              void* d_out, int out_size, void* d_ws, size_t ws_size,
                              hipStream_t stream) {
  const float* tracks = (const float*)d_in[0];
  const float* wih0   = (const float*)d_in[1];
  const float* whh0   = (const float*)d_in[2];
  const float* bih0   = (const float*)d_in[3];
  const float* bhh0   = (const float*)d_in[4];
  const float* wih1   = (const float*)d_in[5];
  const float* whh1   = (const float*)d_in[6];
  const float* bih1   = (const float*)d_in[7];
  const float* bhh1   = (const float*)d_in[8];
  const float* wih2   = (const float*)d_in[9];
  const float* whh2   = (const float*)d_in[10];
  const float* bih2   = (const float*)d_in[11];
  const float* bhh2   = (const float*)d_in[12];
  const float* wpred  = (const float*)d_in[13];
  const float* bpred  = (const float*)d_in[14];
  float* out = (float*)d_out;

  char* ws = (char*)d_ws;
  unsigned short* wre_hi = (unsigned short*)(ws);
  unsigned short* wre_lo = (unsigned short*)(ws + WRE_LO_OFF);
  unsigned short* hb     = (unsigned short*)(ws + HB_OFF);
  unsigned int*   flags  = (unsigned int*)(ws + FLAGS_OFF);

  (void)hipFuncSetAttribute((const void*)lstm_coop,
                            hipFuncAttributeMaxDynamicSharedMemorySize, SMEM_BYTES);

  init_reorder<<<5120, 256, 0, stream>>>(whh0, wih1, whh1, wih2, whh2, wre_hi, wre_lo);
  // zero hb (786432 B) + flags (16384 B) -> 50176 uint4
  init_zero<<<197, 256, 0, stream>>>((uint4*)(ws + HB_OFF), 50176);

  void* args[12];
  args[0]  = (void*)&tracks;
  args[1]  = (void*)&wih0;
  args[2]  = (void*)&bih0;
  args[3]  = (void*)&bhh0;
  args[4]  = (void*)&bih1;
  args[5]  = (void*)&bhh1;
  args[6]  = (void*)&bih2;
  args[7]  = (void*)&bhh2;
  args[8]  = (void*)&wre_hi;
  args[9]  = (void*)&wre_lo;
  args[10] = (void*)&hb;
  args[11] = (void*)&flags;
  // cooperative launch kept purely for the all-blocks-co-resident guarantee
  hipLaunchCooperativeKernel((const void*)lstm_coop, dim3(192), dim3(256), args,
                             SMEM_BYTES, stream);

  head_kernel<<<256, 256, 0, stream>>>(hb, wpred, bpred, out);
}